// Round 19
// baseline (331.156 us; speedup 1.0000x reference)
//
#include <hip/hip_runtime.h>
#include <hip/hip_bf16.h>

#define NN 100000
#define EE 1600000
#define HID 128
#define CLS 40
#define EPSBN 1e-5f
#define NBUK ((NN + 255) >> 8)     // 391 buckets of 256 nodes
#define CAP 6144                   // slots per bucket region
#define EPB 4096                   // edges per p1 block
#define GROWS (NN / 8)             // 12500 partial-stat rows (one per agg block)

typedef float f32x4 __attribute__((ext_vector_type(4)));
typedef float f32x2 __attribute__((ext_vector_type(2)));
typedef short s16x8 __attribute__((ext_vector_type(8)));
union U48 { uint4 u; s16x8 s; };

static __device__ __forceinline__ unsigned short f2bf(float f) {
    unsigned u = __float_as_uint(f);
    unsigned r = (u + 0x7fff + ((u >> 16) & 1)) >> 16;   // RNE
    return (unsigned short)r;
}
static __device__ __forceinline__ unsigned pack2(float a, float b) {
    return (unsigned)f2bf(a) | ((unsigned)f2bf(b) << 16);
}
static __device__ __forceinline__ float bflo(unsigned v) { return __uint_as_float(v << 16); }
static __device__ __forceinline__ float bfhi(unsigned v) { return __uint_as_float(v & 0xffff0000u); }

// ---------------- combined init + W pre-pack ----------------

__global__ void prep_all(const float* __restrict__ W1, const float* __restrict__ W2,
                         const float* __restrict__ W3,
                         unsigned* __restrict__ Wf1, unsigned* __restrict__ Wf2,
                         unsigned* __restrict__ Wf3,
                         int* gcur, float* stats1, float* stats2) {
    int blk = blockIdx.x;
    int tid = threadIdx.x;
    if (blk < 64) {
        const float* W = (blk < 32) ? W1 : W2;
        unsigned* Wf = (blk < 32) ? Wf1 : Wf2;
        int t = ((blk & 31) << 8) + tid;
        int q = t & 3, lane = (t >> 2) & 63, f = t >> 8;
        int ks = f >> 3, ct = f & 7;
        int k = ks * 32 + ((lane >> 4) << 3) + q * 2;
        int col = ct * 16 + (lane & 15);
        Wf[t] = pack2(W[k * 128 + col], W[(k + 1) * 128 + col]);
    } else if (blk < 76) {
        int t = ((blk - 64) << 8) + tid;
        int q = t & 3, lane = (t >> 2) & 63, f = t >> 8;
        int ks = f / 3, ct = f - ks * 3;
        int k = ks * 32 + ((lane >> 4) << 3) + q * 2;
        int col = ct * 16 + (lane & 15);
        float v0 = (col < CLS) ? W3[k * CLS + col] : 0.0f;
        float v1 = (col < CLS) ? W3[(k + 1) * CLS + col] : 0.0f;
        Wf3[t] = pack2(v0, v1);
    } else {
        int j = ((blk - 76) << 8) + tid;
        if (j < NBUK) gcur[j] = j * CAP;
        if (blk == 76) {
            stats1[tid] = 0.0f;
            stats2[tid] = 0.0f;
        }
    }
}

// ---------------- CSR build ----------------

__global__ __launch_bounds__(256) void fill_p1_binned(const int* __restrict__ src,
                                                      const int* __restrict__ dst,
                                                      int* gcur, int* __restrict__ tmp) {
    __shared__ int cnt[NBUK];
    __shared__ int base[NBUK];
    int tid = threadIdx.x;
    for (int j = tid; j < NBUK; j += 256) cnt[j] = 0;
    __syncthreads();

    int es[16], ed[16];
    int i0 = blockIdx.x * EPB;
#pragma unroll
    for (int k = 0; k < 16; k++) {
        int i = i0 + k * 256 + tid;
        bool ok = i < EE;
        es[k] = ok ? src[i] : -1;
        ed[k] = ok ? dst[i] : 0;
        if (ok) atomicAdd(&cnt[ed[k] >> 8], 1);
    }
    __syncthreads();
    for (int j = tid; j < NBUK; j += 256) {
        int c = cnt[j];
        base[j] = c ? atomicAdd(&gcur[j], c) : 0;
        cnt[j] = 0;
    }
    __syncthreads();
#pragma unroll
    for (int k = 0; k < 16; k++) {
        if (es[k] >= 0) {
            int b = ed[k] >> 8;
            int r = atomicAdd(&cnt[b], 1);
            tmp[base[b] + r] = (es[k] << 8) | (ed[k] & 255);
        }
    }
}

__global__ __launch_bounds__(512) void bucket_scan(const int* __restrict__ gcur,
                                                   int* __restrict__ gbase,
                                                   int* __restrict__ row_ptr) {
    __shared__ int sc[512];
    int tid = threadIdx.x;
    int v = (tid < NBUK) ? gcur[tid] - tid * CAP : 0;
    sc[tid] = v;
    __syncthreads();
    for (int off = 1; off < 512; off <<= 1) {
        int t = (tid >= off) ? sc[tid - off] : 0;
        __syncthreads();
        sc[tid] += t;
        __syncthreads();
    }
    if (tid < NBUK) gbase[tid] = sc[tid] - v;
    if (tid == NBUK - 1) {
        gbase[NBUK] = sc[tid];
        row_ptr[NN] = sc[tid];
    }
}

__global__ __launch_bounds__(256) void fill_p2(const int* __restrict__ tmp,
                                               const int* __restrict__ gcur,
                                               const int* __restrict__ gbase,
                                               float* __restrict__ dinv,
                                               int* __restrict__ row_ptr,
                                               int* __restrict__ csr) {
    __shared__ int cnt[256];
    __shared__ int sc[256];
    __shared__ int cur[256];
    int b = blockIdx.x;
    int tid = threadIdx.x;
    int total = gcur[b] - b * CAP;
    cnt[tid] = 0;
    __syncthreads();
    int lo = b * CAP;
    for (int k = tid; k < total; k += 256) atomicAdd(&cnt[tmp[lo + k] & 255], 1);
    __syncthreads();
    int c = cnt[tid];
    sc[tid] = c;
    __syncthreads();
    for (int off = 1; off < 256; off <<= 1) {
        int t = (tid >= off) ? sc[tid - off] : 0;
        __syncthreads();
        sc[tid] += t;
        __syncthreads();
    }
    int node = (b << 8) + tid;
    int rp = gbase[b] + sc[tid] - c;
    if (node < NN) {
        dinv[node] = rsqrtf((float)(c + 1));   // +1 self loop
        row_ptr[node] = rp;
    }
    cur[tid] = rp;
    __syncthreads();
    for (int k = tid; k < total; k += 256) {
        int v = tmp[lo + k];
        int p = atomicAdd(&cur[v & 255], 1);
        csr[p] = ((unsigned)v) >> 8;
    }
}

// ---------------- MFMA GEMMs (LDS-staged A tiles) ----------------

#define LDA 136   // padded row stride in shorts (272B: 2-way LDS aliasing only)

// MODE 0: A = Xf (fp32). MODE 1: A = relu(bn(Xb bf16) + xres fp32).
template <int MODE>
__global__ __launch_bounds__(256) void gemm128_mfma(const float* __restrict__ Xf,
                                                    const unsigned* __restrict__ Xb,
                                                    const unsigned* __restrict__ Wf,
                                                    const float* __restrict__ stats,
                                                    const float* __restrict__ gam,
                                                    const float* __restrict__ bet,
                                                    const float* __restrict__ xres,
                                                    const float* __restrict__ dinv,
                                                    unsigned char* __restrict__ Hb) {
    __shared__ unsigned short As[64 * LDA];
    __shared__ float scs[128];
    __shared__ float shs[128];
    int t = threadIdx.x;
    int lane = t & 63, w = t >> 6;
    int wr = w >> 1, wc = w & 1;
    int blk_row = blockIdx.x * 64;
    const float invN = 1.0f / (float)NN;

    s16x8 b[4][4];
    const uint4* Wv = (const uint4*)Wf;
#pragma unroll
    for (int ks = 0; ks < 4; ks++)
#pragma unroll
        for (int ct = 0; ct < 4; ct++) {
            int f = ks * 8 + wc * 4 + ct;
            U48 u; u.u = Wv[f * 64 + lane];
            b[ks][ct] = u.s;
        }

    if (MODE == 1) {
        if (t < 128) {
            float mean = stats[t] * invN;
            float var = stats[128 + t] * invN - mean * mean;
            float sc = gam[t] * rsqrtf(var + EPSBN);
            scs[t] = sc;
            shs[t] = bet[t] - mean * sc;
        }
        __syncthreads();
        const uint2* H2 = (const uint2*)Xb;
        const float4* R4 = (const float4*)xres;
#pragma unroll
        for (int i = 0; i < 8; i++) {
            int idx = i * 256 + t;
            int row = idx >> 5, c4 = idx & 31;
            int grow = blk_row + row;
            uint2 h = make_uint2(0u, 0u);
            float4 r = make_float4(0, 0, 0, 0);
            if (grow < NN) {
                h = H2[(size_t)grow * 32 + c4];
                r = R4[(size_t)grow * 32 + c4];
            }
            int f0 = c4 * 4;
            float v0 = fmaxf(fmaf(bflo(h.x), scs[f0 + 0], shs[f0 + 0]) + r.x, 0.0f);
            float v1 = fmaxf(fmaf(bfhi(h.x), scs[f0 + 1], shs[f0 + 1]) + r.y, 0.0f);
            float v2 = fmaxf(fmaf(bflo(h.y), scs[f0 + 2], shs[f0 + 2]) + r.z, 0.0f);
            float v3 = fmaxf(fmaf(bfhi(h.y), scs[f0 + 3], shs[f0 + 3]) + r.w, 0.0f);
            *(uint2*)&As[row * LDA + c4 * 4] = make_uint2(pack2(v0, v1), pack2(v2, v3));
        }
    } else {
        const float4* X4 = (const float4*)Xf;
#pragma unroll
        for (int i = 0; i < 8; i++) {
            int idx = i * 256 + t;
            int row = idx >> 5, c4 = idx & 31;
            int grow = blk_row + row;
            float4 a = make_float4(0, 0, 0, 0);
            if (grow < NN) a = X4[(size_t)grow * 32 + c4];
            *(uint2*)&As[row * LDA + c4 * 4] = make_uint2(pack2(a.x, a.y), pack2(a.z, a.w));
        }
    }
    __syncthreads();

    f32x4 acc[2][4] = {};
    int lrow = lane & 15;
    int koff = (lane >> 4) << 3;

#pragma unroll
    for (int ks = 0; ks < 4; ks++) {
        int k0 = ks * 32 + koff;
#pragma unroll
        for (int rf = 0; rf < 2; rf++) {
            int rloc = wr * 32 + rf * 16 + lrow;
            U48 a;
            a.u = *(const uint4*)&As[rloc * LDA + k0];
#pragma unroll
            for (int ct = 0; ct < 4; ct++)
                acc[rf][ct] = __builtin_amdgcn_mfma_f32_16x16x32_bf16(a.s, b[ks][ct], acc[rf][ct], 0, 0, 0);
        }
    }

#pragma unroll
    for (int rf = 0; rf < 2; rf++) {
        int rbase = blk_row + wr * 32 + rf * 16 + ((lane >> 4) << 2);
        float dv[4];
#pragma unroll
        for (int r = 0; r < 4; r++) dv[r] = (rbase + r < NN) ? dinv[rbase + r] : 0.0f;
#pragma unroll
        for (int ct = 0; ct < 4; ct++) {
            int col = wc * 64 + ct * 16 + lrow;
#pragma unroll
            for (int r = 0; r < 4; r++) {
                int row = rbase + r;
                if (row < NN) {
                    int pv = __builtin_amdgcn_cvt_pk_fp8_f32(acc[rf][ct][r] * dv[r], 0.0f, 0, false);
                    Hb[(size_t)row * 128 + col] = (unsigned char)pv;
                }
            }
        }
    }
}

// layer-3: A = relu(bn(Xb bf16)), LDS-staged; out h3S = (A@W3)*dinv, FP8 [N][40]
__global__ __launch_bounds__(256) void gemm40_mfma(const unsigned* __restrict__ Xb,
                                                   const unsigned* __restrict__ Wf,
                                                   const float* __restrict__ stats,
                                                   const float* __restrict__ gam,
                                                   const float* __restrict__ bet,
                                                   const float* __restrict__ dinv,
                                                   unsigned char* __restrict__ H3) {
    __shared__ unsigned short As[64 * LDA];
    __shared__ float scs[128];
    __shared__ float shs[128];
    int t = threadIdx.x;
    int lane = t & 63, w = t >> 6;
    int blk_row = blockIdx.x * 64;
    const float invN = 1.0f / (float)NN;

    s16x8 b[4][3];
    const uint4* Wv = (const uint4*)Wf;
#pragma unroll
    for (int ks = 0; ks < 4; ks++)
#pragma unroll
        for (int ct = 0; ct < 3; ct++) {
            U48 u; u.u = Wv[(ks * 3 + ct) * 64 + lane];
            b[ks][ct] = u.s;
        }

    if (t < 128) {
        float mean = stats[t] * invN;
        float var = stats[128 + t] * invN - mean * mean;
        float sc = gam[t] * rsqrtf(var + EPSBN);
        scs[t] = sc;
        shs[t] = bet[t] - mean * sc;
    }
    __syncthreads();
    const uint2* H2 = (const uint2*)Xb;
#pragma unroll
    for (int i = 0; i < 8; i++) {
        int idx = i * 256 + t;
        int row = idx >> 5, c4 = idx & 31;
        int grow = blk_row + row;
        uint2 h = make_uint2(0u, 0u);
        if (grow < NN) h = H2[(size_t)grow * 32 + c4];
        int f0 = c4 * 4;
        float v0 = fmaxf(fmaf(bflo(h.x), scs[f0 + 0], shs[f0 + 0]), 0.0f);
        float v1 = fmaxf(fmaf(bfhi(h.x), scs[f0 + 1], shs[f0 + 1]), 0.0f);
        float v2 = fmaxf(fmaf(bflo(h.y), scs[f0 + 2], shs[f0 + 2]), 0.0f);
        float v3 = fmaxf(fmaf(bfhi(h.y), scs[f0 + 3], shs[f0 + 3]), 0.0f);
        *(uint2*)&As[row * LDA + c4 * 4] = make_uint2(pack2(v0, v1), pack2(v2, v3));
    }
    __syncthreads();

    f32x4 acc[3] = {};
    int lrow = lane & 15;
    int koff = (lane >> 4) << 3;

#pragma unroll
    for (int ks = 0; ks < 4; ks++) {
        int k0 = ks * 32 + koff;
        int rloc = w * 16 + lrow;
        U48 a;
        a.u = *(const uint4*)&As[rloc * LDA + k0];
#pragma unroll
        for (int ct = 0; ct < 3; ct++)
            acc[ct] = __builtin_amdgcn_mfma_f32_16x16x32_bf16(a.s, b[ks][ct], acc[ct], 0, 0, 0);
    }

    int rbase = blk_row + w * 16 + ((lane >> 4) << 2);
    float dv[4];
#pragma unroll
    for (int r = 0; r < 4; r++) dv[r] = (rbase + r < NN) ? dinv[rbase + r] : 0.0f;
#pragma unroll
    for (int ct = 0; ct < 3; ct++) {
        int col = ct * 16 + lrow;
        if (col >= CLS) continue;
#pragma unroll
        for (int r = 0; r < 4; r++) {
            int row = rbase + r;
            if (row < NN) {
                int pv = __builtin_amdgcn_cvt_pk_fp8_f32(acc[ct][r] * dv[r], 0.0f, 0, false);
                H3[(size_t)row * CLS + col] = (unsigned char)pv;
            }
        }
    }
}

// ---------------- aggregation (factorized row-sum, fused BN partial stats) ----------------

// half-wave per node, fp8 table, 12-deep; csr indices batch-loaded by lanes 0-11
// of each half and shfl-broadcast (1 VMEM + 12 bpermute instead of 12 VMEM).
// Epilogue computes per-block BN partial sums (no atomics) -> gpart row.
__global__ __launch_bounds__(256) void agg128_half(const unsigned* __restrict__ h8,
                                                   const int* __restrict__ row_ptr,
                                                   const int* __restrict__ csr,
                                                   const float* __restrict__ dinv,
                                                   const float* __restrict__ bias,
                                                   uint2* __restrict__ outb,
                                                   float* __restrict__ gpart) {
    __shared__ float red[4][256];
    int tid = threadIdx.x;
    int wid = tid >> 6;
    int lane = tid & 63;
    int half = lane >> 5, l = lane & 31;
    int node = blockIdx.x * 8 + wid * 2 + half;

    unsigned sv = h8[(size_t)node * 32 + l];
    f32x2 alo = __builtin_amdgcn_cvt_pk_f32_fp8(sv, false);
    f32x2 ahi = __builtin_amdgcn_cvt_pk_f32_fp8(sv, true);

    int beg = row_ptr[node], end = row_ptr[node + 1];
    int cnt = end - beg;
    int cmax = max(cnt, __shfl_xor(cnt, 32));
    int hb = (lane & 32);    // shfl base of own half

    for (int k = 0; k < cmax; k += 12) {
        // batch csr load: lanes 0-11 of each half fetch 12 consecutive indices
        int bidx = beg + k + l;
        int cl = (bidx < end) ? bidx : beg;
        int myv = (l < 12) ? csr[cl] : 0;
        unsigned g[12];
#pragma unroll
        for (int j = 0; j < 12; j++) {
            int si = __shfl(myv, hb + j);
            int idx = beg + k + j;
            g[j] = (idx < end) ? h8[(size_t)si * 32 + l] : 0u;
        }
#pragma unroll
        for (int j = 0; j < 12; j++) {
            alo += __builtin_amdgcn_cvt_pk_f32_fp8(g[j], false);
            ahi += __builtin_amdgcn_cvt_pk_f32_fp8(g[j], true);
        }
    }

    float di = dinv[node];
    float4 b = *(const float4*)&bias[l * 4];
    float o0 = fmaf(alo.x, di, b.x), o1 = fmaf(alo.y, di, b.y);
    float o2 = fmaf(ahi.x, di, b.z), o3 = fmaf(ahi.y, di, b.w);
    outb[(size_t)node * 32 + l] = make_uint2(pack2(o0, o1), pack2(o2, o3));

    // fused BN partial stats: lane l (both halves) owns features 4l..4l+3
    float s0 = o0, s1 = o1, s2 = o2, s3 = o3;
    float q0 = o0 * o0, q1 = o1 * o1, q2 = o2 * o2, q3 = o3 * o3;
    s0 += __shfl_xor(s0, 32); s1 += __shfl_xor(s1, 32);
    s2 += __shfl_xor(s2, 32); s3 += __shfl_xor(s3, 32);
    q0 += __shfl_xor(q0, 32); q1 += __shfl_xor(q1, 32);
    q2 += __shfl_xor(q2, 32); q3 += __shfl_xor(q3, 32);
    if (half == 0) {
        red[wid][l * 4 + 0] = s0; red[wid][l * 4 + 1] = s1;
        red[wid][l * 4 + 2] = s2; red[wid][l * 4 + 3] = s3;
        red[wid][128 + l * 4 + 0] = q0; red[wid][128 + l * 4 + 1] = q1;
        red[wid][128 + l * 4 + 2] = q2; red[wid][128 + l * 4 + 3] = q3;
    }
    __syncthreads();
    float pv = red[0][tid] + red[1][tid] + red[2][tid] + red[3][tid];
    gpart[(size_t)blockIdx.x * 256 + tid] = pv;
}

// layer-3: TWO nodes per wave (half-wave each: 3 slots x 10 lanes), fp8 table,
// f32x2 packed accumulation, half-local 5-step softmax butterflies.
__global__ __launch_bounds__(256) void agg40_lsm(const unsigned* __restrict__ h3,
                                                 const int* __restrict__ row_ptr,
                                                 const int* __restrict__ csr,
                                                 const float* __restrict__ dinv,
                                                 const float* __restrict__ b3,
                                                 float* __restrict__ out) {
    int wid = threadIdx.x >> 6;
    int lane = threadIdx.x & 63;
    int half = lane >> 5, l30 = lane & 31;
    int slot = l30 / 10;
    int fp = l30 - slot * 10;
    bool sok = slot < 3;
    int node = blockIdx.x * 8 + wid * 2 + half;

    f32x2 alo = {0.0f, 0.0f}, ahi = {0.0f, 0.0f};
    if (slot == 0) {
        unsigned v = h3[(size_t)node * 10 + fp];
        alo = __builtin_amdgcn_cvt_pk_f32_fp8(v, false);
        ahi = __builtin_amdgcn_cvt_pk_f32_fp8(v, true);
    }
    int beg = row_ptr[node], end = row_ptr[node + 1];
    int cnt = end - beg;
    for (int k = 0; k < cnt; k += 12) {
#pragma unroll
        for (int jj = 0; jj < 4; jj++) {
            int idx = beg + k + jj * 3 + slot;
            bool on = sok && (idx < end);
            int s = csr[on ? idx : beg];
            unsigned g = on ? h3[(size_t)s * 10 + fp] : 0u;
            alo += __builtin_amdgcn_cvt_pk_f32_fp8(g, false);
            ahi += __builtin_amdgcn_cvt_pk_f32_fp8(g, true);
        }
    }
    float a0 = alo.x, a1 = alo.y, a2 = ahi.x, a3 = ahi.y;
    float t0 = __shfl(a0, lane + 10), t1 = __shfl(a1, lane + 10);
    float t2 = __shfl(a2, lane + 10), t3 = __shfl(a3, lane + 10);
    float u0 = __shfl(a0, lane + 20), u1 = __shfl(a1, lane + 20);
    float u2 = __shfl(a2, lane + 20), u3 = __shfl(a3, lane + 20);
    bool fin = l30 < 10;
    float l0 = 0.0f, l1 = 0.0f, l2 = 0.0f, l3 = 0.0f;
    if (fin) {
        float di = dinv[node];
        float4 b = *(const float4*)&b3[fp * 4];
        l0 = fmaf(a0 + t0 + u0, di, b.x);
        l1 = fmaf(a1 + t1 + u1, di, b.y);
        l2 = fmaf(a2 + t2 + u2, di, b.z);
        l3 = fmaf(a3 + t3 + u3, di, b.w);
    }
    float m = fin ? fmaxf(fmaxf(l0, l1), fmaxf(l2, l3)) : -1e30f;
#pragma unroll
    for (int off = 16; off > 0; off >>= 1) m = fmaxf(m, __shfl_xor(m, off));
    float s = fin ? (expf(l0 - m) + expf(l1 - m) + expf(l2 - m) + expf(l3 - m)) : 0.0f;
#pragma unroll
    for (int off = 16; off > 0; off >>= 1) s += __shfl_xor(s, off);
    float lse = m + logf(s);
    if (fin)
        *(float4*)&out[(size_t)node * CLS + fp * 4] =
            make_float4(l0 - lse, l1 - lse, l2 - lse, l3 - lse);
}

// ---------------- BN finalize: sum 12500 partial rows, 64 atomics/address ----------------

__global__ __launch_bounds__(256) void bn_final(const float* __restrict__ gpart,
                                                float* __restrict__ stats) {
    int t = threadIdx.x;
    int k0 = blockIdx.x * 196;
    int k1 = (k0 + 196 < GROWS) ? k0 + 196 : GROWS;
    float s = 0.0f;
    for (int k = k0; k < k1; k++)
        s += gpart[(size_t)k * 256 + t];
    if (k0 < GROWS) atomicAdd(&stats[t], s);
}

// ---------------- launcher ----------------

extern "C" void kernel_launch(void* const* d_in, const int* in_sizes, int n_in,
                              void* d_out, int out_size, void* d_ws, size_t ws_size,
                              hipStream_t stream) {
    const float* x   = (const float*)d_in[0];
    const int*   ei  = (const int*)d_in[1];
    const float* W1  = (const float*)d_in[2];
    const float* b1  = (const float*)d_in[3];
    const float* g1  = (const float*)d_in[4];
    const float* be1 = (const float*)d_in[5];
    const float* W2  = (const float*)d_in[6];
    const float* b2  = (const float*)d_in[7];
    const float* g2  = (const float*)d_in[8];
    const float* be2 = (const float*)d_in[9];
    const float* W3  = (const float*)d_in[10];
    const float* b3  = (const float*)d_in[11];
    float* out = (float*)d_out;

    const int* src = ei;
    const int* dst = ei + EE;

    char* w = (char*)d_ws;
    size_t off = 0;
    auto alloc = [&](size_t bytes) {
        void* p = w + off;
        off += (bytes + 255) & ~(size_t)255;
        return p;
    };
    float* dinv      = (float*)alloc((size_t)NN * 4);
    int*   row_ptr   = (int*)alloc((size_t)(NN + 1) * 4);
    int*   gcur      = (int*)alloc((size_t)NBUK * 4);
    int*   gbase     = (int*)alloc((size_t)(NBUK + 1) * 4);
    int*   tmp       = (int*)alloc((size_t)NBUK * CAP * 4);
    int*   csr       = (int*)alloc((size_t)EE * 4);           // src only
    float* stats1    = (float*)alloc(256 * 4);
    float* stats2    = (float*)alloc(256 * 4);
    float* gpart     = (float*)alloc((size_t)GROWS * 256 * 4); // 12.8MB partials
    unsigned* Wf1    = (unsigned*)alloc(8192 * 4);
    unsigned* Wf2    = (unsigned*)alloc(8192 * 4);
    unsigned* Wf3    = (unsigned*)alloc(3072 * 4);
    unsigned* aH     = (unsigned*)alloc((size_t)NN * 64 * 4); // bf16 agg output (post-bias)
    unsigned char* hB8 = (unsigned char*)alloc((size_t)NN * 128); // fp8 hS table (12.8MB)
    unsigned char* h3b = (unsigned char*)alloc((size_t)NN * 40);  // fp8 h3S table (4MB)

    const int NB_P1 = (EE + EPB - 1) / EPB;
    const int NB_G  = (NN + 63) / 64;

    // ---- CSR build + weight prep ----
    prep_all<<<78, 256, 0, stream>>>(W1, W2, W3, Wf1, Wf2, Wf3, gcur, stats1, stats2);
    fill_p1_binned<<<NB_P1, 256, 0, stream>>>(src, dst, gcur, tmp);
    bucket_scan<<<1, 512, 0, stream>>>(gcur, gbase, row_ptr);
    fill_p2<<<NBUK, 256, 0, stream>>>(tmp, gcur, gbase, dinv, row_ptr, csr);

    // ---- layer 1 ----
    gemm128_mfma<0><<<NB_G, 256, 0, stream>>>(x, nullptr, Wf1, nullptr, nullptr, nullptr, nullptr, dinv, hB8);
    agg128_half<<<NN / 8, 256, 0, stream>>>((const unsigned*)hB8, row_ptr, csr, dinv, b1, (uint2*)aH, gpart);
    bn_final<<<64, 256, 0, stream>>>(gpart, stats1);

    // ---- layer 2 (BN1 finalize + residual + relu fused into staging) ----
    gemm128_mfma<1><<<NB_G, 256, 0, stream>>>(nullptr, aH, Wf2, stats1, g1, be1, x, dinv, hB8);
    agg128_half<<<NN / 8, 256, 0, stream>>>((const unsigned*)hB8, row_ptr, csr, dinv, b2, (uint2*)aH, gpart);
    bn_final<<<64, 256, 0, stream>>>(gpart, stats2);

    // ---- layer 3 (BN2 finalize + relu fused into staging) ----
    gemm40_mfma<<<NB_G, 256, 0, stream>>>(aH, Wf3, stats2, g2, be2, dinv, h3b);
    agg40_lsm<<<NN / 8, 256, 0, stream>>>((const unsigned*)h3b, row_ptr, csr, dinv, b3, out);
}

// Round 20
// 264.049 us; speedup vs baseline: 1.2541x; 1.2541x over previous
//
#include <hip/hip_runtime.h>
#include <hip/hip_bf16.h>

#define NN 100000
#define EE 1600000
#define HID 128
#define CLS 40
#define EPSBN 1e-5f
#define NBUK ((NN + 255) >> 8)     // 391 buckets of 256 nodes
#define CAP 6144                   // slots per bucket region
#define EPB 4096                   // edges per p1 block
#define GROWS (NN / 8)             // 12500 partial-stat rows (one per agg block)
#define FINB 500                   // bn_final blocks (25 rows each)

typedef float f32x4 __attribute__((ext_vector_type(4)));
typedef float f32x2 __attribute__((ext_vector_type(2)));
typedef short s16x8 __attribute__((ext_vector_type(8)));
union U48 { uint4 u; s16x8 s; };

static __device__ __forceinline__ unsigned short f2bf(float f) {
    unsigned u = __float_as_uint(f);
    unsigned r = (u + 0x7fff + ((u >> 16) & 1)) >> 16;   // RNE
    return (unsigned short)r;
}
static __device__ __forceinline__ unsigned pack2(float a, float b) {
    return (unsigned)f2bf(a) | ((unsigned)f2bf(b) << 16);
}
static __device__ __forceinline__ float bflo(unsigned v) { return __uint_as_float(v << 16); }
static __device__ __forceinline__ float bfhi(unsigned v) { return __uint_as_float(v & 0xffff0000u); }

// ---------------- combined init + W pre-pack ----------------

__global__ void prep_all(const float* __restrict__ W1, const float* __restrict__ W2,
                         const float* __restrict__ W3,
                         unsigned* __restrict__ Wf1, unsigned* __restrict__ Wf2,
                         unsigned* __restrict__ Wf3,
                         int* gcur, float* stats1, float* stats2) {
    int blk = blockIdx.x;
    int tid = threadIdx.x;
    if (blk < 64) {
        const float* W = (blk < 32) ? W1 : W2;
        unsigned* Wf = (blk < 32) ? Wf1 : Wf2;
        int t = ((blk & 31) << 8) + tid;
        int q = t & 3, lane = (t >> 2) & 63, f = t >> 8;
        int ks = f >> 3, ct = f & 7;
        int k = ks * 32 + ((lane >> 4) << 3) + q * 2;
        int col = ct * 16 + (lane & 15);
        Wf[t] = pack2(W[k * 128 + col], W[(k + 1) * 128 + col]);
    } else if (blk < 76) {
        int t = ((blk - 64) << 8) + tid;
        int q = t & 3, lane = (t >> 2) & 63, f = t >> 8;
        int ks = f / 3, ct = f - ks * 3;
        int k = ks * 32 + ((lane >> 4) << 3) + q * 2;
        int col = ct * 16 + (lane & 15);
        float v0 = (col < CLS) ? W3[k * CLS + col] : 0.0f;
        float v1 = (col < CLS) ? W3[(k + 1) * CLS + col] : 0.0f;
        Wf3[t] = pack2(v0, v1);
    } else {
        int j = ((blk - 76) << 8) + tid;
        if (j < NBUK) gcur[j] = j * CAP;
        if (blk == 76) {
            stats1[tid] = 0.0f;
            stats2[tid] = 0.0f;
        }
    }
}

// ---------------- CSR build ----------------

__global__ __launch_bounds__(256) void fill_p1_binned(const int* __restrict__ src,
                                                      const int* __restrict__ dst,
                                                      int* gcur, int* __restrict__ tmp) {
    __shared__ int cnt[NBUK];
    __shared__ int base[NBUK];
    int tid = threadIdx.x;
    for (int j = tid; j < NBUK; j += 256) cnt[j] = 0;
    __syncthreads();

    int es[16], ed[16];
    int i0 = blockIdx.x * EPB;
#pragma unroll
    for (int k = 0; k < 16; k++) {
        int i = i0 + k * 256 + tid;
        bool ok = i < EE;
        es[k] = ok ? src[i] : -1;
        ed[k] = ok ? dst[i] : 0;
        if (ok) atomicAdd(&cnt[ed[k] >> 8], 1);
    }
    __syncthreads();
    for (int j = tid; j < NBUK; j += 256) {
        int c = cnt[j];
        base[j] = c ? atomicAdd(&gcur[j], c) : 0;
        cnt[j] = 0;
    }
    __syncthreads();
#pragma unroll
    for (int k = 0; k < 16; k++) {
        if (es[k] >= 0) {
            int b = ed[k] >> 8;
            int r = atomicAdd(&cnt[b], 1);
            tmp[base[b] + r] = (es[k] << 8) | (ed[k] & 255);
        }
    }
}

__global__ __launch_bounds__(512) void bucket_scan(const int* __restrict__ gcur,
                                                   int* __restrict__ gbase,
                                                   int* __restrict__ row_ptr) {
    __shared__ int sc[512];
    int tid = threadIdx.x;
    int v = (tid < NBUK) ? gcur[tid] - tid * CAP : 0;
    sc[tid] = v;
    __syncthreads();
    for (int off = 1; off < 512; off <<= 1) {
        int t = (tid >= off) ? sc[tid - off] : 0;
        __syncthreads();
        sc[tid] += t;
        __syncthreads();
    }
    if (tid < NBUK) gbase[tid] = sc[tid] - v;
    if (tid == NBUK - 1) {
        gbase[NBUK] = sc[tid];
        row_ptr[NN] = sc[tid];
    }
}

__global__ __launch_bounds__(256) void fill_p2(const int* __restrict__ tmp,
                                               const int* __restrict__ gcur,
                                               const int* __restrict__ gbase,
                                               float* __restrict__ dinv,
                                               int* __restrict__ row_ptr,
                                               int* __restrict__ csr) {
    __shared__ int cnt[256];
    __shared__ int sc[256];
    __shared__ int cur[256];
    int b = blockIdx.x;
    int tid = threadIdx.x;
    int total = gcur[b] - b * CAP;
    cnt[tid] = 0;
    __syncthreads();
    int lo = b * CAP;
    for (int k = tid; k < total; k += 256) atomicAdd(&cnt[tmp[lo + k] & 255], 1);
    __syncthreads();
    int c = cnt[tid];
    sc[tid] = c;
    __syncthreads();
    for (int off = 1; off < 256; off <<= 1) {
        int t = (tid >= off) ? sc[tid - off] : 0;
        __syncthreads();
        sc[tid] += t;
        __syncthreads();
    }
    int node = (b << 8) + tid;
    int rp = gbase[b] + sc[tid] - c;
    if (node < NN) {
        dinv[node] = rsqrtf((float)(c + 1));   // +1 self loop
        row_ptr[node] = rp;
    }
    cur[tid] = rp;
    __syncthreads();
    for (int k = tid; k < total; k += 256) {
        int v = tmp[lo + k];
        int p = atomicAdd(&cur[v & 255], 1);
        csr[p] = ((unsigned)v) >> 8;
    }
}

// ---------------- MFMA GEMMs (LDS-staged A tiles) ----------------

#define LDA 136   // padded row stride in shorts (272B: 2-way LDS aliasing only)

// MODE 0: A = Xf (fp32). MODE 1: A = relu(bn(Xb bf16) + xres fp32).
template <int MODE>
__global__ __launch_bounds__(256) void gemm128_mfma(const float* __restrict__ Xf,
                                                    const unsigned* __restrict__ Xb,
                                                    const unsigned* __restrict__ Wf,
                                                    const float* __restrict__ stats,
                                                    const float* __restrict__ gam,
                                                    const float* __restrict__ bet,
                                                    const float* __restrict__ xres,
                                                    const float* __restrict__ dinv,
                                                    unsigned char* __restrict__ Hb) {
    __shared__ unsigned short As[64 * LDA];
    __shared__ float scs[128];
    __shared__ float shs[128];
    int t = threadIdx.x;
    int lane = t & 63, w = t >> 6;
    int wr = w >> 1, wc = w & 1;
    int blk_row = blockIdx.x * 64;
    const float invN = 1.0f / (float)NN;

    s16x8 b[4][4];
    const uint4* Wv = (const uint4*)Wf;
#pragma unroll
    for (int ks = 0; ks < 4; ks++)
#pragma unroll
        for (int ct = 0; ct < 4; ct++) {
            int f = ks * 8 + wc * 4 + ct;
            U48 u; u.u = Wv[f * 64 + lane];
            b[ks][ct] = u.s;
        }

    if (MODE == 1) {
        if (t < 128) {
            float mean = stats[t] * invN;
            float var = stats[128 + t] * invN - mean * mean;
            float sc = gam[t] * rsqrtf(var + EPSBN);
            scs[t] = sc;
            shs[t] = bet[t] - mean * sc;
        }
        __syncthreads();
        const uint2* H2 = (const uint2*)Xb;
        const float4* R4 = (const float4*)xres;
#pragma unroll
        for (int i = 0; i < 8; i++) {
            int idx = i * 256 + t;
            int row = idx >> 5, c4 = idx & 31;
            int grow = blk_row + row;
            uint2 h = make_uint2(0u, 0u);
            float4 r = make_float4(0, 0, 0, 0);
            if (grow < NN) {
                h = H2[(size_t)grow * 32 + c4];
                r = R4[(size_t)grow * 32 + c4];
            }
            int f0 = c4 * 4;
            float v0 = fmaxf(fmaf(bflo(h.x), scs[f0 + 0], shs[f0 + 0]) + r.x, 0.0f);
            float v1 = fmaxf(fmaf(bfhi(h.x), scs[f0 + 1], shs[f0 + 1]) + r.y, 0.0f);
            float v2 = fmaxf(fmaf(bflo(h.y), scs[f0 + 2], shs[f0 + 2]) + r.z, 0.0f);
            float v3 = fmaxf(fmaf(bfhi(h.y), scs[f0 + 3], shs[f0 + 3]) + r.w, 0.0f);
            *(uint2*)&As[row * LDA + c4 * 4] = make_uint2(pack2(v0, v1), pack2(v2, v3));
        }
    } else {
        const float4* X4 = (const float4*)Xf;
#pragma unroll
        for (int i = 0; i < 8; i++) {
            int idx = i * 256 + t;
            int row = idx >> 5, c4 = idx & 31;
            int grow = blk_row + row;
            float4 a = make_float4(0, 0, 0, 0);
            if (grow < NN) a = X4[(size_t)grow * 32 + c4];
            *(uint2*)&As[row * LDA + c4 * 4] = make_uint2(pack2(a.x, a.y), pack2(a.z, a.w));
        }
    }
    __syncthreads();

    f32x4 acc[2][4] = {};
    int lrow = lane & 15;
    int koff = (lane >> 4) << 3;

#pragma unroll
    for (int ks = 0; ks < 4; ks++) {
        int k0 = ks * 32 + koff;
#pragma unroll
        for (int rf = 0; rf < 2; rf++) {
            int rloc = wr * 32 + rf * 16 + lrow;
            U48 a;
            a.u = *(const uint4*)&As[rloc * LDA + k0];
#pragma unroll
            for (int ct = 0; ct < 4; ct++)
                acc[rf][ct] = __builtin_amdgcn_mfma_f32_16x16x32_bf16(a.s, b[ks][ct], acc[rf][ct], 0, 0, 0);
        }
    }

#pragma unroll
    for (int rf = 0; rf < 2; rf++) {
        int rbase = blk_row + wr * 32 + rf * 16 + ((lane >> 4) << 2);
        float dv[4];
#pragma unroll
        for (int r = 0; r < 4; r++) dv[r] = (rbase + r < NN) ? dinv[rbase + r] : 0.0f;
#pragma unroll
        for (int ct = 0; ct < 4; ct++) {
            int col = wc * 64 + ct * 16 + lrow;
#pragma unroll
            for (int r = 0; r < 4; r++) {
                int row = rbase + r;
                if (row < NN) {
                    int pv = __builtin_amdgcn_cvt_pk_fp8_f32(acc[rf][ct][r] * dv[r], 0.0f, 0, false);
                    Hb[(size_t)row * 128 + col] = (unsigned char)pv;
                }
            }
        }
    }
}

// layer-3: A = relu(bn(Xb bf16)), LDS-staged; out h3S = (A@W3)*dinv, FP8 [N][40]
__global__ __launch_bounds__(256) void gemm40_mfma(const unsigned* __restrict__ Xb,
                                                   const unsigned* __restrict__ Wf,
                                                   const float* __restrict__ stats,
                                                   const float* __restrict__ gam,
                                                   const float* __restrict__ bet,
                                                   const float* __restrict__ dinv,
                                                   unsigned char* __restrict__ H3) {
    __shared__ unsigned short As[64 * LDA];
    __shared__ float scs[128];
    __shared__ float shs[128];
    int t = threadIdx.x;
    int lane = t & 63, w = t >> 6;
    int blk_row = blockIdx.x * 64;
    const float invN = 1.0f / (float)NN;

    s16x8 b[4][3];
    const uint4* Wv = (const uint4*)Wf;
#pragma unroll
    for (int ks = 0; ks < 4; ks++)
#pragma unroll
        for (int ct = 0; ct < 3; ct++) {
            U48 u; u.u = Wv[(ks * 3 + ct) * 64 + lane];
            b[ks][ct] = u.s;
        }

    if (t < 128) {
        float mean = stats[t] * invN;
        float var = stats[128 + t] * invN - mean * mean;
        float sc = gam[t] * rsqrtf(var + EPSBN);
        scs[t] = sc;
        shs[t] = bet[t] - mean * sc;
    }
    __syncthreads();
    const uint2* H2 = (const uint2*)Xb;
#pragma unroll
    for (int i = 0; i < 8; i++) {
        int idx = i * 256 + t;
        int row = idx >> 5, c4 = idx & 31;
        int grow = blk_row + row;
        uint2 h = make_uint2(0u, 0u);
        if (grow < NN) h = H2[(size_t)grow * 32 + c4];
        int f0 = c4 * 4;
        float v0 = fmaxf(fmaf(bflo(h.x), scs[f0 + 0], shs[f0 + 0]), 0.0f);
        float v1 = fmaxf(fmaf(bfhi(h.x), scs[f0 + 1], shs[f0 + 1]), 0.0f);
        float v2 = fmaxf(fmaf(bflo(h.y), scs[f0 + 2], shs[f0 + 2]), 0.0f);
        float v3 = fmaxf(fmaf(bfhi(h.y), scs[f0 + 3], shs[f0 + 3]), 0.0f);
        *(uint2*)&As[row * LDA + c4 * 4] = make_uint2(pack2(v0, v1), pack2(v2, v3));
    }
    __syncthreads();

    f32x4 acc[3] = {};
    int lrow = lane & 15;
    int koff = (lane >> 4) << 3;

#pragma unroll
    for (int ks = 0; ks < 4; ks++) {
        int k0 = ks * 32 + koff;
        int rloc = w * 16 + lrow;
        U48 a;
        a.u = *(const uint4*)&As[rloc * LDA + k0];
#pragma unroll
        for (int ct = 0; ct < 3; ct++)
            acc[ct] = __builtin_amdgcn_mfma_f32_16x16x32_bf16(a.s, b[ks][ct], acc[ct], 0, 0, 0);
    }

    int rbase = blk_row + w * 16 + ((lane >> 4) << 2);
    float dv[4];
#pragma unroll
    for (int r = 0; r < 4; r++) dv[r] = (rbase + r < NN) ? dinv[rbase + r] : 0.0f;
#pragma unroll
    for (int ct = 0; ct < 3; ct++) {
        int col = ct * 16 + lrow;
        if (col >= CLS) continue;
#pragma unroll
        for (int r = 0; r < 4; r++) {
            int row = rbase + r;
            if (row < NN) {
                int pv = __builtin_amdgcn_cvt_pk_fp8_f32(acc[ct][r] * dv[r], 0.0f, 0, false);
                H3[(size_t)row * CLS + col] = (unsigned char)pv;
            }
        }
    }
}

// ---------------- aggregation (factorized row-sum, fused BN partial stats) ----------------

__global__ __launch_bounds__(256) void agg128_half(const unsigned* __restrict__ h8,
                                                   const int* __restrict__ row_ptr,
                                                   const int* __restrict__ csr,
                                                   const float* __restrict__ dinv,
                                                   const float* __restrict__ bias,
                                                   uint2* __restrict__ outb,
                                                   float* __restrict__ gpart) {
    __shared__ float red[4][256];
    int tid = threadIdx.x;
    int wid = tid >> 6;
    int lane = tid & 63;
    int half = lane >> 5, l = lane & 31;
    int node = blockIdx.x * 8 + wid * 2 + half;

    unsigned sv = h8[(size_t)node * 32 + l];
    f32x2 alo = __builtin_amdgcn_cvt_pk_f32_fp8(sv, false);
    f32x2 ahi = __builtin_amdgcn_cvt_pk_f32_fp8(sv, true);

    int beg = row_ptr[node], end = row_ptr[node + 1];
    int cnt = end - beg;
    int cmax = max(cnt, __shfl_xor(cnt, 32));
    int hb = (lane & 32);    // shfl base of own half

    for (int k = 0; k < cmax; k += 12) {
        int bidx = beg + k + l;
        int cl = (bidx < end) ? bidx : beg;
        int myv = (l < 12) ? csr[cl] : 0;
        unsigned g[12];
#pragma unroll
        for (int j = 0; j < 12; j++) {
            int si = __shfl(myv, hb + j);
            int idx = beg + k + j;
            g[j] = (idx < end) ? h8[(size_t)si * 32 + l] : 0u;
        }
#pragma unroll
        for (int j = 0; j < 12; j++) {
            alo += __builtin_amdgcn_cvt_pk_f32_fp8(g[j], false);
            ahi += __builtin_amdgcn_cvt_pk_f32_fp8(g[j], true);
        }
    }

    float di = dinv[node];
    float4 b = *(const float4*)&bias[l * 4];
    float o0 = fmaf(alo.x, di, b.x), o1 = fmaf(alo.y, di, b.y);
    float o2 = fmaf(ahi.x, di, b.z), o3 = fmaf(ahi.y, di, b.w);
    outb[(size_t)node * 32 + l] = make_uint2(pack2(o0, o1), pack2(o2, o3));

    float s0 = o0, s1 = o1, s2 = o2, s3 = o3;
    float q0 = o0 * o0, q1 = o1 * o1, q2 = o2 * o2, q3 = o3 * o3;
    s0 += __shfl_xor(s0, 32); s1 += __shfl_xor(s1, 32);
    s2 += __shfl_xor(s2, 32); s3 += __shfl_xor(s3, 32);
    q0 += __shfl_xor(q0, 32); q1 += __shfl_xor(q1, 32);
    q2 += __shfl_xor(q2, 32); q3 += __shfl_xor(q3, 32);
    if (half == 0) {
        red[wid][l * 4 + 0] = s0; red[wid][l * 4 + 1] = s1;
        red[wid][l * 4 + 2] = s2; red[wid][l * 4 + 3] = s3;
        red[wid][128 + l * 4 + 0] = q0; red[wid][128 + l * 4 + 1] = q1;
        red[wid][128 + l * 4 + 2] = q2; red[wid][128 + l * 4 + 3] = q3;
    }
    __syncthreads();
    float pv = red[0][tid] + red[1][tid] + red[2][tid] + red[3][tid];
    gpart[(size_t)blockIdx.x * 256 + tid] = pv;
}

// layer-3: TWO nodes per wave (half-wave each: 3 slots x 10 lanes), fp8 table
__global__ __launch_bounds__(256) void agg40_lsm(const unsigned* __restrict__ h3,
                                                 const int* __restrict__ row_ptr,
                                                 const int* __restrict__ csr,
                                                 const float* __restrict__ dinv,
                                                 const float* __restrict__ b3,
                                                 float* __restrict__ out) {
    int wid = threadIdx.x >> 6;
    int lane = threadIdx.x & 63;
    int half = lane >> 5, l30 = lane & 31;
    int slot = l30 / 10;
    int fp = l30 - slot * 10;
    bool sok = slot < 3;
    int node = blockIdx.x * 8 + wid * 2 + half;

    f32x2 alo = {0.0f, 0.0f}, ahi = {0.0f, 0.0f};
    if (slot == 0) {
        unsigned v = h3[(size_t)node * 10 + fp];
        alo = __builtin_amdgcn_cvt_pk_f32_fp8(v, false);
        ahi = __builtin_amdgcn_cvt_pk_f32_fp8(v, true);
    }
    int beg = row_ptr[node], end = row_ptr[node + 1];
    int cnt = end - beg;
    for (int k = 0; k < cnt; k += 12) {
#pragma unroll
        for (int jj = 0; jj < 4; jj++) {
            int idx = beg + k + jj * 3 + slot;
            bool on = sok && (idx < end);
            int s = csr[on ? idx : beg];
            unsigned g = on ? h3[(size_t)s * 10 + fp] : 0u;
            alo += __builtin_amdgcn_cvt_pk_f32_fp8(g, false);
            ahi += __builtin_amdgcn_cvt_pk_f32_fp8(g, true);
        }
    }
    float a0 = alo.x, a1 = alo.y, a2 = ahi.x, a3 = ahi.y;
    float t0 = __shfl(a0, lane + 10), t1 = __shfl(a1, lane + 10);
    float t2 = __shfl(a2, lane + 10), t3 = __shfl(a3, lane + 10);
    float u0 = __shfl(a0, lane + 20), u1 = __shfl(a1, lane + 20);
    float u2 = __shfl(a2, lane + 20), u3 = __shfl(a3, lane + 20);
    bool fin = l30 < 10;
    float l0 = 0.0f, l1 = 0.0f, l2 = 0.0f, l3 = 0.0f;
    if (fin) {
        float di = dinv[node];
        float4 b = *(const float4*)&b3[fp * 4];
        l0 = fmaf(a0 + t0 + u0, di, b.x);
        l1 = fmaf(a1 + t1 + u1, di, b.y);
        l2 = fmaf(a2 + t2 + u2, di, b.z);
        l3 = fmaf(a3 + t3 + u3, di, b.w);
    }
    float m = fin ? fmaxf(fmaxf(l0, l1), fmaxf(l2, l3)) : -1e30f;
#pragma unroll
    for (int off = 16; off > 0; off >>= 1) m = fmaxf(m, __shfl_xor(m, off));
    float s = fin ? (expf(l0 - m) + expf(l1 - m) + expf(l2 - m) + expf(l3 - m)) : 0.0f;
#pragma unroll
    for (int off = 16; off > 0; off >>= 1) s += __shfl_xor(s, off);
    float lse = m + logf(s);
    if (fin)
        *(float4*)&out[(size_t)node * CLS + fp * 4] =
            make_float4(l0 - lse, l1 - lse, l2 - lse, l3 - lse);
}

// ---------------- BN finalize: 500 blocks x 25 rows, coalesced, 500 atomics/addr ----------------

__global__ __launch_bounds__(256) void bn_final(const float* __restrict__ gpart,
                                                float* __restrict__ stats) {
    int t = threadIdx.x;
    int k0 = blockIdx.x * 25;
    float s = 0.0f;
#pragma unroll 5
    for (int k = k0; k < k0 + 25; k++)
        s += gpart[(size_t)k * 256 + t];
    atomicAdd(&stats[t], s);
}

// ---------------- launcher ----------------

extern "C" void kernel_launch(void* const* d_in, const int* in_sizes, int n_in,
                              void* d_out, int out_size, void* d_ws, size_t ws_size,
                              hipStream_t stream) {
    const float* x   = (const float*)d_in[0];
    const int*   ei  = (const int*)d_in[1];
    const float* W1  = (const float*)d_in[2];
    const float* b1  = (const float*)d_in[3];
    const float* g1  = (const float*)d_in[4];
    const float* be1 = (const float*)d_in[5];
    const float* W2  = (const float*)d_in[6];
    const float* b2  = (const float*)d_in[7];
    const float* g2  = (const float*)d_in[8];
    const float* be2 = (const float*)d_in[9];
    const float* W3  = (const float*)d_in[10];
    const float* b3  = (const float*)d_in[11];
    float* out = (float*)d_out;

    const int* src = ei;
    const int* dst = ei + EE;

    char* w = (char*)d_ws;
    size_t off = 0;
    auto alloc = [&](size_t bytes) {
        void* p = w + off;
        off += (bytes + 255) & ~(size_t)255;
        return p;
    };
    float* dinv      = (float*)alloc((size_t)NN * 4);
    int*   row_ptr   = (int*)alloc((size_t)(NN + 1) * 4);
    int*   gcur      = (int*)alloc((size_t)NBUK * 4);
    int*   gbase     = (int*)alloc((size_t)(NBUK + 1) * 4);
    int*   tmp       = (int*)alloc((size_t)NBUK * CAP * 4);
    int*   csr       = (int*)alloc((size_t)EE * 4);           // src only
    float* stats1    = (float*)alloc(256 * 4);
    float* stats2    = (float*)alloc(256 * 4);
    float* gpart     = (float*)alloc((size_t)GROWS * 256 * 4); // 12.8MB partials
    unsigned* Wf1    = (unsigned*)alloc(8192 * 4);
    unsigned* Wf2    = (unsigned*)alloc(8192 * 4);
    unsigned* Wf3    = (unsigned*)alloc(3072 * 4);
    unsigned* aH     = (unsigned*)alloc((size_t)NN * 64 * 4); // bf16 agg output (post-bias)
    unsigned char* hB8 = (unsigned char*)alloc((size_t)NN * 128); // fp8 hS table (12.8MB)
    unsigned char* h3b = (unsigned char*)alloc((size_t)NN * 40);  // fp8 h3S table (4MB)

    const int NB_P1 = (EE + EPB - 1) / EPB;
    const int NB_G  = (NN + 63) / 64;

    // ---- CSR build + weight prep ----
    prep_all<<<78, 256, 0, stream>>>(W1, W2, W3, Wf1, Wf2, Wf3, gcur, stats1, stats2);
    fill_p1_binned<<<NB_P1, 256, 0, stream>>>(src, dst, gcur, tmp);
    bucket_scan<<<1, 512, 0, stream>>>(gcur, gbase, row_ptr);
    fill_p2<<<NBUK, 256, 0, stream>>>(tmp, gcur, gbase, dinv, row_ptr, csr);

    // ---- layer 1 ----
    gemm128_mfma<0><<<NB_G, 256, 0, stream>>>(x, nullptr, Wf1, nullptr, nullptr, nullptr, nullptr, dinv, hB8);
    agg128_half<<<NN / 8, 256, 0, stream>>>((const unsigned*)hB8, row_ptr, csr, dinv, b1, (uint2*)aH, gpart);
    bn_final<<<FINB, 256, 0, stream>>>(gpart, stats1);

    // ---- layer 2 (BN1 finalize + residual + relu fused into staging) ----
    gemm128_mfma<1><<<NB_G, 256, 0, stream>>>(nullptr, aH, Wf2, stats1, g1, be1, x, dinv, hB8);
    agg128_half<<<NN / 8, 256, 0, stream>>>((const unsigned*)hB8, row_ptr, csr, dinv, b2, (uint2*)aH, gpart);
    bn_final<<<FINB, 256, 0, stream>>>(gpart, stats2);

    // ---- layer 3 (BN2 finalize + relu fused into staging) ----
    gemm40_mfma<<<NB_G, 256, 0, stream>>>(aH, Wf3, stats2, g2, be2, dinv, h3b);
    agg40_lsm<<<NN / 8, 256, 0, stream>>>((const unsigned*)h3b, row_ptr, csr, dinv, b3, out);
}